// Round 14
// baseline (3781.448 us; speedup 1.0000x reference)
//
#include <hip/hip_runtime.h>
#include <hip/hip_bf16.h>

#define Hdim 1024
#define TST  127
#define NCLS 50000
#define POLL_GUARD (1 << 17)

typedef __attribute__((ext_vector_type(8))) short    s8v;   // 8 x bf16
typedef __attribute__((ext_vector_type(4))) float    f4v;   // MFMA acc
typedef __attribute__((ext_vector_type(2))) unsigned u2v;   // packed 4 x bf16

// ---- workspace layout (bytes) ----
#define OFF_X0   0ull
#define SZ_X0    ((unsigned long long)TST * 64 * Hdim * 2ull)   // 16,646,144 bf16 X0
#define OFF_W0B  (OFF_X0 + SZ_X0)                                // 2 MB bf16 embedding W0
#define OFF_WSB  (OFF_W0B + 2097152ull)                          // 12 MB bf16 Ws[6]
#define OFF_ACT  (OFF_WSB + 12582912ull)                         // 8 xcd x 4 bufs x 16 KB
#define OFF_HB   (OFF_ACT + 524288ull)                           // final h [64][1024] bf16
#define OFF_FLG  (OFF_HB + 131072ull)                            // flags[8][4][128] + ranks[8]
#define WS_NEED  (OFF_FLG + 16448ull)

__device__ __forceinline__ unsigned short f2b(float f) {
  union { float f; unsigned u; } v; v.f = f;
  return (unsigned short)((v.u + 0x7FFFu + ((v.u >> 16) & 1u)) >> 16);  // RNE
}
__device__ __forceinline__ float b2f(unsigned short u) {
  union { unsigned u; float f; } v; v.u = ((unsigned)u) << 16;
  return v.f;
}
__device__ __forceinline__ float fast_tanh(float x) { return 1.f - 2.f / (__expf(2.f * x) + 1.f); }
__device__ __forceinline__ float fast_sigm(float x) { return 1.f / (1.f + __expf(-x)); }
__device__ __forceinline__ s8v pack8(const float* __restrict__ p) {
  s8v r;
#pragma unroll
  for (int i = 0; i < 8; ++i) r[i] = (short)f2b(p[i]);
  return r;
}
__device__ __forceinline__ u2v pk4(float a, float b, float c, float d) {
  u2v v;
  v[0] = (unsigned)f2b(a) | ((unsigned)f2b(b) << 16);
  v[1] = (unsigned)f2b(c) | ((unsigned)f2b(d) << 16);
  return v;
}

// ---- access helpers: sc1 = L3 coherence point; sc0 = L1-bypass, own-XCD L2 ----
__device__ __forceinline__ void st_sc1_u32(unsigned* p, unsigned v) {
  asm volatile("global_store_dword %0, %1, off sc0 sc1" :: "v"(p), "v"(v) : "memory");
}
__device__ __forceinline__ void st_sc0_u32(unsigned* p, unsigned v) {
  asm volatile("global_store_dword %0, %1, off sc0" :: "v"(p), "v"(v) : "memory");
}
__device__ __forceinline__ void st_sc0_64(unsigned short* p, u2v v) {
  asm volatile("global_store_dwordx2 %0, %1, off sc0" :: "v"(p), "v"(v) : "memory");
}
__device__ __forceinline__ void wait_vm0() { asm volatile("s_waitcnt vmcnt(0)" ::: "memory"); }

// poll 128 sc1 flags: one u64 per lane (R2-proven shape), guard against hangs
__device__ __forceinline__ void pollg64(const unsigned long long* fb, unsigned tgt) {
  const unsigned long long* p = fb + (threadIdx.x & 63);
  int gd = 0;
  for (;;) {
    unsigned long long v;
    asm volatile("global_load_dwordx2 %0, %1, off sc0 sc1\n\ts_waitcnt vmcnt(0)"
                 : "=v"(v) : "v"(p) : "memory");
    if (__all((int)(((unsigned)v >= tgt) & ((unsigned)(v >> 32) >= tgt)))) break;
    if (++gd >= POLL_GUARD) break;
  }
}

// 8 sc0 dwordx4 act loads + drain in ONE asm block (9 operands, proven scale)
#define GL8S0(B, P) asm volatile(                                       \
  "global_load_dwordx4 %0, %8, off sc0\n\t"                             \
  "global_load_dwordx4 %1, %8, off offset:64 sc0\n\t"                   \
  "global_load_dwordx4 %2, %8, off offset:128 sc0\n\t"                  \
  "global_load_dwordx4 %3, %8, off offset:192 sc0\n\t"                  \
  "global_load_dwordx4 %4, %8, off offset:256 sc0\n\t"                  \
  "global_load_dwordx4 %5, %8, off offset:320 sc0\n\t"                  \
  "global_load_dwordx4 %6, %8, off offset:384 sc0\n\t"                  \
  "global_load_dwordx4 %7, %8, off offset:448 sc0\n\t"                  \
  "s_waitcnt vmcnt(0)"                                                  \
  : "=&v"(B[0]), "=&v"(B[1]), "=&v"(B[2]), "=&v"(B[3]),                 \
    "=&v"(B[4]), "=&v"(B[5]), "=&v"(B[6]), "=&v"(B[7])                  \
  : "v"(P) : "memory")

// ---------------- fp32 -> bf16 bulk convert (W0 and Ws) ----------------
__global__ __launch_bounds__(256) void k_cvt(const float* __restrict__ src,
                                             unsigned short* __restrict__ dst) {
  const int i = (blockIdx.x * 256 + threadIdx.x) * 4;
  float4 v = *(const float4*)(src + i);
  ushort4 o; o.x = f2b(v.x); o.y = f2b(v.y); o.z = f2b(v.z); o.w = f2b(v.w);
  *(ushort4*)(dst + i) = o;
}

// ---------------- X0[t] = emb[idx[:,t+1]] @ W0^T + b0 + bs0, bf16 out ----------------
__global__ __launch_bounds__(256) void k_x0(const float* __restrict__ emb,
                                            const int* __restrict__ ids,
                                            const unsigned short* __restrict__ w0b,
                                            const float* __restrict__ b0,
                                            const float* __restrict__ bs,
                                            unsigned short* __restrict__ x0b) {
  const int t  = blockIdx.x;            // 0..126
  const int cb = blockIdx.y * 256;
  const int lane = threadIdx.x & 63, wvv = threadIdx.x >> 6;
  const int lc = lane & 15, lg = lane >> 4;
  const int cw = cb + wvv * 64;
  const float* erow[4];
#pragma unroll
  for (int rt = 0; rt < 4; ++rt)
    erow[rt] = emb + (size_t)ids[(rt * 16 + lc) * 128 + t + 1] * Hdim + lg * 8;
  f4v acc[4][4];   // [ct][rt]
#pragma unroll
  for (int ct = 0; ct < 4; ++ct)
#pragma unroll
    for (int rt = 0; rt < 4; ++rt) acc[ct][rt] = (f4v){0.f, 0.f, 0.f, 0.f};

  for (int ks = 0; ks < 32; ++ks) {
    s8v bf[4];
#pragma unroll
    for (int rt = 0; rt < 4; ++rt) bf[rt] = pack8(erow[rt] + ks * 32);
#pragma unroll
    for (int ct = 0; ct < 4; ++ct) {
      s8v a = *(const s8v*)(w0b + (size_t)(cw + ct * 16 + lc) * Hdim + ks * 32 + lg * 8);
#pragma unroll
      for (int rt = 0; rt < 4; ++rt)
        acc[ct][rt] = __builtin_amdgcn_mfma_f32_16x16x32_bf16(a, bf[rt], acc[ct][rt], 0, 0, 0);
    }
  }
  unsigned short* xt = x0b + (size_t)t * (64 * Hdim);
#pragma unroll
  for (int ct = 0; ct < 4; ++ct) {
    const int colq = cw + ct * 16 + lg * 4;
    float4 bias = *(const float4*)(b0 + colq);
    float4 bsv  = *(const float4*)(bs + colq);     // bs row 0
#pragma unroll
    for (int rt = 0; rt < 4; ++rt) {
      const int row = rt * 16 + lc;
      ushort4 o;
      o.x = f2b(acc[ct][rt][0] + bias.x + bsv.x);
      o.y = f2b(acc[ct][rt][1] + bias.y + bsv.y);
      o.z = f2b(acc[ct][rt][2] + bias.z + bsv.z);
      o.w = f2b(acc[ct][rt][3] + bias.w + bsv.w);
      *(ushort4*)(xt + (size_t)row * Hdim + colq) = o;
    }
  }
}

// ---------------- persistent scan: 8 XCD-local chains, wave-autonomous reduce ----------------
__global__ __launch_bounds__(256, 1) void k_scan(const float* __restrict__ bs,
                                                 const float* __restrict__ h_in,
                                                 const float* __restrict__ Wsum,
                                                 const float* __restrict__ bsum,
                                                 const float* __restrict__ act,
                                                 char* __restrict__ ws) {
  __shared__ float part[2][2][4][8][36];  // [ping][out][wave][row][36-pad]: 36 KB
  __shared__ char  pad_lds[49152];        // total ~85 KB -> 1 WG/CU -> 32 WG/XCD
  __shared__ int   s_info[2];

  const int tid = threadIdx.x;
  ((volatile char*)pad_lds)[tid] = (char)tid;
  asm volatile("" :: "v"((int)((volatile char*)pad_lds)[tid]));

  const int lane = tid & 63, wv = tid >> 6;
  const int lc = lane & 15, lg = lane >> 4;
  const int lr = lc & 7;                  // MFMA act row (rows 8..15 duplicate)
  const int lr2 = lane & 7, q = (lane >> 3) & 1;  // strip-reduce lane map (lane<16)
  const int co = wv * 8 + q * 4;          // this lane's 4-col quad (local 0..31)

  unsigned* flg_all = (unsigned*)(ws + OFF_FLG);
  unsigned* ranks   = flg_all + 4096;     // after 8*4*128 flags

  if (tid == 0) {
    unsigned x;
    asm volatile("s_getreg_b32 %0, hwreg(HW_REG_XCC_ID)" : "=s"(x));
    x &= 7u;
    unsigned rr = __hip_atomic_fetch_add(&ranks[x], 1u, __ATOMIC_RELAXED, __HIP_MEMORY_SCOPE_AGENT);
    s_info[0] = (int)x; s_info[1] = (int)rr;
  }
  __syncthreads();
  const int xcd = s_info[0];
  const int r   = s_info[1];
  if (r >= 32) return;                    // pigeonhole (1 WG/CU) makes this unreachable
  const int c0w = r * 32;
  const int fidx = r * 4 + wv;            // this wave's flag slot in each group

  unsigned short* actX = (unsigned short*)(ws + OFF_ACT) + (size_t)xcd * 32768;
  unsigned short* hL  = actX;             // [8][1024] bf16 per buffer
  unsigned short* n1L = actX + 8192;
  unsigned short* n3L = actX + 16384;
  unsigned short* n5L = actX + 24576;
  unsigned* flgX = flg_all + xcd * 512;   // [4 groups][128]
  unsigned* gn1 = flgX;
  unsigned* gn3 = flgX + 128;
  unsigned* gn5 = flgX + 256;
  unsigned* gh  = flgX + 384;
  const unsigned short* wsb = (const unsigned short*)(ws + OFF_WSB);
  const unsigned short* x0b = (const unsigned short*)(ws + OFF_X0);
  unsigned short* HB = (unsigned short*)(ws + OFF_HB);

  // softmax combine weights over leaves {2,4,6} -> Wsum rows {1,3,5}
  float cw0, cw1, cw2;
  {
    float c[3];
#pragma unroll
    for (int j = 0; j < 3; ++j) {
      const int i = 2 * j + 1;
      float s = bsum[i];
      for (int a2 = 0; a2 < 12; ++a2) s += Wsum[i * 12 + a2] * act[a2];
      c[j] = s;
    }
    float m = fmaxf(c[0], fmaxf(c[1], c[2]));
    float e0 = __expf(c[0] - m), e1 = __expf(c[1] - m), e2 = __expf(c[2] - m);
    float inv = 1.f / (e0 + e1 + e2);
    cw0 = e0 * inv; cw1 = e1 * inv; cw2 = e2 * inv;
  }

  // ---- preload resident weights Ws[1..5]: per wave 2 col-tiles x 8 k-chunks each ----
  const size_t wbase = (size_t)(c0w + lc) * Hdim + (size_t)wv * 256 + lg * 8;
  const size_t wct   = (size_t)16 * Hdim;
  s8v w1f[2][8], w2f[2][8], w3f[2][8], w4f[2][8], w5f[2][8];
#pragma unroll
  for (int i = 0; i < 8; ++i) {
    w1f[0][i] = *(const s8v*)(wsb + 1u * 1048576u + wbase + i * 32);
    w1f[1][i] = *(const s8v*)(wsb + 1u * 1048576u + wbase + wct + i * 32);
    w2f[0][i] = *(const s8v*)(wsb + 2u * 1048576u + wbase + i * 32);
    w2f[1][i] = *(const s8v*)(wsb + 2u * 1048576u + wbase + wct + i * 32);
    w3f[0][i] = *(const s8v*)(wsb + 3u * 1048576u + wbase + i * 32);
    w3f[1][i] = *(const s8v*)(wsb + 3u * 1048576u + wbase + wct + i * 32);
    w4f[0][i] = *(const s8v*)(wsb + 4u * 1048576u + wbase + i * 32);
    w4f[1][i] = *(const s8v*)(wsb + 4u * 1048576u + wbase + wct + i * 32);
    w5f[0][i] = *(const s8v*)(wsb + 5u * 1048576u + wbase + i * 32);
    w5f[1][i] = *(const s8v*)(wsb + 5u * 1048576u + wbase + wct + i * 32);
  }

  // ---- init: publish h(0) slice (sc0, own L2); every wave flags its slot ----
  if (tid < 128) {
    const int row = tid >> 4, cp = (tid & 15) * 2;
    const float* hp = h_in + (size_t)(xcd * 8 + row) * Hdim + c0w + cp;
    unsigned pk = (unsigned)f2b(hp[0]) | ((unsigned)f2b(hp[1]) << 16);
    st_sc0_u32((unsigned*)(hL + (size_t)row * Hdim + c0w + cp), pk);
  }
  wait_vm0();
  __syncthreads();
  if (lane == 0) st_sc1_u32(gh + fidx, 1u);

  const f4v z4 = (f4v){0.f, 0.f, 0.f, 0.f};
  f4v n2reg = z4, n4reg = z4;             // leaf strips live in the reduce lane's regs

  for (int t = 0; t < TST; ++t) {
    const unsigned tq = (unsigned)t + 1u;
    // ======== L1: n1 = tanh(Ws0 h + X0[t])  (Ws0 streamed; part ping A, out 0) ========
    pollg64((const unsigned long long*)gh, tq);
    {
      s8v bb[8];
      GL8S0(bb, hL + (size_t)lr * Hdim + wv * 256 + lg * 8);
      unsigned long long w0a = (unsigned long long)wsb;
      asm volatile("" : "+v"(w0a));                  // launder: keep M0 loads in-loop
      const unsigned short* w0p = (const unsigned short*)w0a;
      f4v a0 = z4, a1 = z4;
#pragma unroll
      for (int i = 0; i < 8; ++i) {
        s8v wA = *(const s8v*)(w0p + wbase + i * 32);
        s8v wB = *(const s8v*)(w0p + wbase + wct + i * 32);
        a0 = __builtin_amdgcn_mfma_f32_16x16x32_bf16(wA, bb[i], a0, 0, 0, 0);
        a1 = __builtin_amdgcn_mfma_f32_16x16x32_bf16(wB, bb[i], a1, 0, 0, 0);
      }
      if (lc < 8) {
        *(f4v*)&part[0][0][wv][lc][lg * 4] = a0;
        *(f4v*)&part[0][0][wv][lc][16 + lg * 4] = a1;
      }
    }
    __syncthreads();
    if (lane < 16) {
      f4v s = *(f4v*)&part[0][0][0][lr2][co] + *(f4v*)&part[0][0][1][lr2][co]
            + *(f4v*)&part[0][0][2][lr2][co] + *(f4v*)&part[0][0][3][lr2][co];
      ushort4 xu = *(const ushort4*)(x0b + (size_t)t * 65536 +
                                     (size_t)(xcd * 8 + lr2) * Hdim + c0w + co);
      st_sc0_64(n1L + (size_t)lr2 * Hdim + c0w + co,
                pk4(fast_tanh(s[0] + b2f(xu.x)), fast_tanh(s[1] + b2f(xu.y)),
                    fast_tanh(s[2] + b2f(xu.z)), fast_tanh(s[3] + b2f(xu.w))));
    }
    wait_vm0();
    if (lane == 0) st_sc1_u32(gn1 + fidx, tq);

    // ======== L2: n3 = sigm(Ws2 n1 + bs2) [out0]; n2 = relu(Ws1 n1 + bs1) [out1->regs] ========
    pollg64((const unsigned long long*)gn1, tq);
    {
      s8v bb[8];
      GL8S0(bb, n1L + (size_t)lr * Hdim + wv * 256 + lg * 8);
      f4v a20 = z4, a21 = z4, a10 = z4, a11 = z4;
#pragma unroll
      for (int i = 0; i < 8; ++i) {
        a20 = __builtin_amdgcn_mfma_f32_16x16x32_bf16(w2f[0][i], bb[i], a20, 0, 0, 0);
        a21 = __builtin_amdgcn_mfma_f32_16x16x32_bf16(w2f[1][i], bb[i], a21, 0, 0, 0);
        a10 = __builtin_amdgcn_mfma_f32_16x16x32_bf16(w1f[0][i], bb[i], a10, 0, 0, 0);
        a11 = __builtin_amdgcn_mfma_f32_16x16x32_bf16(w1f[1][i], bb[i], a11, 0, 0, 0);
      }
      if (lc < 8) {
        *(f4v*)&part[1][0][wv][lc][lg * 4] = a20;
        *(f4v*)&part[1][0][wv][lc][16 + lg * 4] = a21;
        *(f4v*)&part[1][1][wv][lc][lg * 4] = a10;
        *(f4v*)&part[1][1][wv][lc][16 + lg * 4] = a11;
      }
    }
    __syncthreads();
    if (lane < 16) {
      f4v s3 = *(f4v*)&part[1][0][0][lr2][co] + *(f4v*)&part[1][0][1][lr2][co]
             + *(f4v*)&part[1][0][2][lr2][co] + *(f4v*)&part[1][0][3][lr2][co];
      f4v s2 = *(f4v*)&part[1][1][0][lr2][co] + *(f4v*)&part[1][1][1][lr2][co]
             + *(f4v*)&part[1][1][2][lr2][co] + *(f4v*)&part[1][1][3][lr2][co];
      f4v b3 = *(const f4v*)(bs + 2 * Hdim + c0w + co);
      f4v b2 = *(const f4v*)(bs + 1 * Hdim + c0w + co);
      st_sc0_64(n3L + (size_t)lr2 * Hdim + c0w + co,
                pk4(fast_sigm(s3[0] + b3[0]), fast_sigm(s3[1] + b3[1]),
                    fast_sigm(s3[2] + b3[2]), fast_sigm(s3[3] + b3[3])));
      n2reg[0] = fmaxf(s2[0] + b2[0], 0.f); n2reg[1] = fmaxf(s2[1] + b2[1], 0.f);
      n2reg[2] = fmaxf(s2[2] + b2[2], 0.f); n2reg[3] = fmaxf(s2[3] + b2[3], 0.f);
    }
    wait_vm0();
    if (lane == 0) st_sc1_u32(gn3 + fidx, tq);

    // ======== L3: n5 = relu(Ws4 n3 + bs4) [out0]; n4 = tanh(Ws3 n3 + bs3) [out1->regs] ========
    pollg64((const unsigned long long*)gn3, tq);
    {
      s8v bb[8];
      GL8S0(bb, n3L + (size_t)lr * Hdim + wv * 256 + lg * 8);
      f4v a40 = z4, a41 = z4, a30 = z4, a31 = z4;
#pragma unroll
      for (int i = 0; i < 8; ++i) {
        a40 = __builtin_amdgcn_mfma_f32_16x16x32_bf16(w4f[0][i], bb[i], a40, 0, 0, 0);
        a41 = __builtin_amdgcn_mfma_f32_16x16x32_bf16(w4f[1][i], bb[i], a41, 0, 0, 0);
        a30 = __builtin_amdgcn_mfma_f32_16x16x32_bf16(w3f[0][i], bb[i], a30, 0, 0, 0);
        a31 = __builtin_amdgcn_mfma_f32_16x16x32_bf16(w3f[1][i], bb[i], a31, 0, 0, 0);
      }
      if (lc < 8) {
        *(f4v*)&part[0][0][wv][lc][lg * 4] = a40;
        *(f4v*)&part[0][0][wv][lc][16 + lg * 4] = a41;
        *(f4v*)&part[0][1][wv][lc][lg * 4] = a30;
        *(f4v*)&part[0][1][wv][lc][16 + lg * 4] = a31;
      }
    }
    __syncthreads();
    if (lane < 16) {
      f4v s5 = *(f4v*)&part[0][0][0][lr2][co] + *(f4v*)&part[0][0][1][lr2][co]
             + *(f4v*)&part[0][0][2][lr2][co] + *(f4v*)&part[0][0][3][lr2][co];
      f4v s4 = *(f4v*)&part[0][1][0][lr2][co] + *(f4v*)&part[0][1][1][lr2][co]
             + *(f4v*)&part[0][1][2][lr2][co] + *(f4v*)&part[0][1][3][lr2][co];
      f4v b5 = *(const f4v*)(bs + 4 * Hdim + c0w + co);
      f4v b4 = *(const f4v*)(bs + 3 * Hdim + c0w + co);
      st_sc0_64(n5L + (size_t)lr2 * Hdim + c0w + co,
                pk4(fmaxf(s5[0] + b5[0], 0.f), fmaxf(s5[1] + b5[1], 0.f),
                    fmaxf(s5[2] + b5[2], 0.f), fmaxf(s5[3] + b5[3], 0.f)));
      n4reg[0] = fast_tanh(s4[0] + b4[0]); n4reg[1] = fast_tanh(s4[1] + b4[1]);
      n4reg[2] = fast_tanh(s4[2] + b4[2]); n4reg[3] = fast_tanh(s4[3] + b4[3]);
    }
    wait_vm0();
    if (lane == 0) st_sc1_u32(gn5 + fidx, tq);

    // ======== L4: n6 = tanh(Ws5 n5 + bs5); h' = cw.(n2reg, n4reg, n6) ========
    pollg64((const unsigned long long*)gn5, tq);
    {
      s8v bb[8];
      GL8S0(bb, n5L + (size_t)lr * Hdim + wv * 256 + lg * 8);
      f4v a0 = z4, a1 = z4;
#pragma unroll
      for (int i = 0; i < 8; ++i) {
        a0 = __builtin_amdgcn_mfma_f32_16x16x32_bf16(w5f[0][i], bb[i], a0, 0, 0, 0);
        a1 = __builtin_amdgcn_mfma_f32_16x16x32_bf16(w5f[1][i], bb[i], a1, 0, 0, 0);
      }
      if (lc < 8) {
        *(f4v*)&part[1][0][wv][lc][lg * 4] = a0;
        *(f4v*)&part[1][0][wv][lc][16 + lg * 4] = a1;
      }
    }
    __syncthreads();
    if (lane < 16) {
      f4v s = *(f4v*)&part[1][0][0][lr2][co] + *(f4v*)&part[1][0][1][lr2][co]
            + *(f4v*)&part[1][0][2][lr2][co] + *(f4v*)&part[1][0][3][lr2][co];
      f4v b6 = *(const f4v*)(bs + 5 * Hdim + c0w + co);
      float hv[4];
#pragma unroll
      for (int j = 0; j < 4; ++j) {
        const float n6 = fast_tanh(s[j] + b6[j]);
        hv[j] = cw0 * n2reg[j] + cw1 * n4reg[j] + cw2 * n6;
      }
      u2v pk = pk4(hv[0], hv[1], hv[2], hv[3]);
      st_sc0_64(hL + (size_t)lr2 * Hdim + c0w + co, pk);
      if (t == TST - 1)
        *(u2v*)(HB + (size_t)(xcd * 8 + lr2) * Hdim + c0w + co) = pk;
    }
    wait_vm0();
    if (lane == 0) st_sc1_u32(gh + fidx, tq + 1u);
  }
}

// ---------------- epilogue: out = h @ W_out^T + b_out ----------------
__global__ __launch_bounds__(256) void k_out(const unsigned short* __restrict__ hb,
                                             const float* __restrict__ wout,
                                             const float* __restrict__ bout,
                                             float* __restrict__ out) {
  const int cb = blockIdx.x * 128;
  const int lane = threadIdx.x & 63, wvv = threadIdx.x >> 6;
  const int lc = lane & 15, lg = lane >> 4;
  const int cw = cb + wvv * 32;
  f4v acc[4][2];
#pragma unroll
  for (int rt = 0; rt < 4; ++rt)
#pragma unroll
    for (int ct = 0; ct < 2; ++ct) acc[rt][ct] = (f4v){0.f, 0.f, 0.f, 0.f};

  for (int ks = 0; ks < 32; ++ks) {
    s8v a[4];
#pragma unroll
    for (int rt = 0; rt < 4; ++rt)
      a[rt] = *(const s8v*)(hb + (rt * 16 + lc) * Hdim + ks * 32 + lg * 8);
#pragma unroll
    for (int ct = 0; ct < 2; ++ct) {
      const int col = cw + ct * 16 + lc;
      const int cs = col < NCLS ? col : NCLS - 1;
      s8v b = pack8(wout + (size_t)cs * Hdim + ks * 32 + lg * 8);
#pragma unroll
      for (int rt = 0; rt < 4; ++rt)
        acc[rt][ct] = __builtin_amdgcn_mfma_f32_16x16x32_bf16(a[rt], b, acc[rt][ct], 0, 0, 0);
    }
  }
#pragma unroll
  for (int ct = 0; ct < 2; ++ct) {
    const int col = cw + ct * 16 + lc;
    if (col < NCLS) {
      const float bias = bout[col];
#pragma unroll
      for (int rt = 0; rt < 4; ++rt)
#pragma unroll
        for (int j = 0; j < 4; ++j)
          out[(size_t)(rt * 16 + lg * 4 + j) * NCLS + col] = acc[rt][ct][j] + bias;
    }
  }
}

extern "C" void kernel_launch(void* const* d_in, const int* in_sizes, int n_in,
                              void* d_out, int out_size, void* d_ws, size_t ws_size,
                              hipStream_t stream) {
  (void)in_sizes; (void)n_in; (void)out_size;
  if (ws_size < WS_NEED) return;

  const float* emb  = (const float*)d_in[0];
  const float* h0   = (const float*)d_in[1];
  const int*   ids  = (const int*)d_in[2];
  const float* W0   = (const float*)d_in[3];
  const float* b0   = (const float*)d_in[4];
  const float* Ws   = (const float*)d_in[5];
  const float* bsp  = (const float*)d_in[6];
  const float* Wout = (const float*)d_in[7];
  const float* bout = (const float*)d_in[8];
  const float* Wsum = (const float*)d_in[9];
  const float* bsum = (const float*)d_in[10];
  const float* actv = (const float*)d_in[11];
  char* ws  = (char*)d_ws;
  float* out = (float*)d_out;

  hipMemsetAsync(ws + OFF_FLG, 0, 16448, stream);                     // flags + ranks
  k_cvt<<<1024, 256, 0, stream>>>(W0, (unsigned short*)(ws + OFF_W0B));
  k_cvt<<<6144, 256, 0, stream>>>(Ws, (unsigned short*)(ws + OFF_WSB));
  k_x0<<<dim3(TST, 4), 256, 0, stream>>>(emb, ids, (const unsigned short*)(ws + OFF_W0B),
                                         b0, bsp, (unsigned short*)(ws + OFF_X0));

  void* args[] = { (void*)&bsp, (void*)&h0, (void*)&Wsum,
                   (void*)&bsum, (void*)&actv, (void*)&ws };
  hipError_t e = hipLaunchCooperativeKernel((void*)k_scan, dim3(256), dim3(256), args, 0, stream);
  if (e != hipSuccess) {
    // fallback: 1 WG/CU forced by ~85 KB LDS -> 256 WGs co-resident anyway;
    // all polls guarded -> worst case wrong answer, never a hang.
    k_scan<<<dim3(256), dim3(256), 0, stream>>>(bsp, h0, Wsum, bsum, actv, ws);
  }

  k_out<<<391, 256, 0, stream>>>((const unsigned short*)(ws + OFF_HB), Wout, bout, out);
}

// Round 15
// 2793.068 us; speedup vs baseline: 1.3539x; 1.3539x over previous
//
#include <hip/hip_runtime.h>
#include <hip/hip_bf16.h>

#define Hdim 1024
#define TST  127
#define NCLS 50000
#define POLL_GUARD (1 << 17)

typedef __attribute__((ext_vector_type(8))) short    s8v;   // 8 x bf16
typedef __attribute__((ext_vector_type(4))) float    f4v;   // MFMA acc
typedef __attribute__((ext_vector_type(2))) unsigned u2v;   // packed 4 x bf16

// ---- workspace layout (bytes) ----
#define OFF_X0   0ull
#define SZ_X0    ((unsigned long long)TST * 64 * Hdim * 2ull)   // 16,646,144 bf16 X0
#define OFF_W0B  (OFF_X0 + SZ_X0)                                // 2 MB bf16 embedding W0
#define OFF_WSB  (OFF_W0B + 2097152ull)                          // 12 MB bf16 Ws[6]
#define OFF_ACT  (OFF_WSB + 12582912ull)                         // 8 xcd x 2 chain x 4 bufs x 8 KB
#define OFF_HB   (OFF_ACT + 524288ull)                           // final h [64][1024] bf16
#define OFF_FLG  (OFF_HB + 131072ull)                            // flags[8][2][4][32] + ranks[8]
#define WS_NEED  (OFF_FLG + 16448ull)

__device__ __forceinline__ unsigned short f2b(float f) {
  union { float f; unsigned u; } v; v.f = f;
  return (unsigned short)((v.u + 0x7FFFu + ((v.u >> 16) & 1u)) >> 16);  // RNE
}
__device__ __forceinline__ float b2f(unsigned short u) {
  union { unsigned u; float f; } v; v.u = ((unsigned)u) << 16;
  return v.f;
}
__device__ __forceinline__ float fast_tanh(float x) { return 1.f - 2.f / (__expf(2.f * x) + 1.f); }
__device__ __forceinline__ float fast_sigm(float x) { return 1.f / (1.f + __expf(-x)); }
__device__ __forceinline__ s8v pack8(const float* __restrict__ p) {
  s8v r;
#pragma unroll
  for (int i = 0; i < 8; ++i) r[i] = (short)f2b(p[i]);
  return r;
}
__device__ __forceinline__ u2v pk4(float a, float b, float c, float d) {
  u2v v;
  v[0] = (unsigned)f2b(a) | ((unsigned)f2b(b) << 16);
  v[1] = (unsigned)f2b(c) | ((unsigned)f2b(d) << 16);
  return v;
}

// ---- access helpers: sc1 = L3 coherence point; sc0 = L1-bypass, own-XCD L2 ----
__device__ __forceinline__ void st_sc1_u32(unsigned* p, unsigned v) {
  asm volatile("global_store_dword %0, %1, off sc0 sc1" :: "v"(p), "v"(v) : "memory");
}
__device__ __forceinline__ void st_sc0_u32(unsigned* p, unsigned v) {
  asm volatile("global_store_dword %0, %1, off sc0" :: "v"(p), "v"(v) : "memory");
}
__device__ __forceinline__ void st_sc0_64(unsigned short* p, u2v v) {
  asm volatile("global_store_dwordx2 %0, %1, off sc0" :: "v"(p), "v"(v) : "memory");
}
__device__ __forceinline__ void wait_vm0() { asm volatile("s_waitcnt vmcnt(0)" ::: "memory"); }

// poll 32 sc1 flags (lane & 31) >= tgt; one load + drain per iter (R3 lesson: one block)
__device__ __forceinline__ void pollg(const unsigned* fb, unsigned tgt) {
  const unsigned* p = fb + (threadIdx.x & 31);
  int gd = 0;
  for (;;) {
    unsigned v;
    asm volatile("global_load_dword %0, %1, off sc0 sc1\n\ts_waitcnt vmcnt(0)"
                 : "=v"(v) : "v"(p) : "memory");
    if (__all((int)(v >= tgt))) break;
    if (++gd >= POLL_GUARD) break;
  }
}

// 8 sc0 dwordx4 act loads + drain in ONE asm block (9 operands, proven scale)
#define GL8S0(B, P) asm volatile(                                       \
  "global_load_dwordx4 %0, %8, off sc0\n\t"                             \
  "global_load_dwordx4 %1, %8, off offset:64 sc0\n\t"                   \
  "global_load_dwordx4 %2, %8, off offset:128 sc0\n\t"                  \
  "global_load_dwordx4 %3, %8, off offset:192 sc0\n\t"                  \
  "global_load_dwordx4 %4, %8, off offset:256 sc0\n\t"                  \
  "global_load_dwordx4 %5, %8, off offset:320 sc0\n\t"                  \
  "global_load_dwordx4 %6, %8, off offset:384 sc0\n\t"                  \
  "global_load_dwordx4 %7, %8, off offset:448 sc0\n\t"                  \
  "s_waitcnt vmcnt(0)"                                                  \
  : "=&v"(B[0]), "=&v"(B[1]), "=&v"(B[2]), "=&v"(B[3]),                 \
    "=&v"(B[4]), "=&v"(B[5]), "=&v"(B[6]), "=&v"(B[7])                  \
  : "v"(P) : "memory")

// ---------------- fp32 -> bf16 bulk convert (W0 and Ws) ----------------
__global__ __launch_bounds__(256) void k_cvt(const float* __restrict__ src,
                                             unsigned short* __restrict__ dst) {
  const int i = (blockIdx.x * 256 + threadIdx.x) * 4;
  float4 v = *(const float4*)(src + i);
  ushort4 o; o.x = f2b(v.x); o.y = f2b(v.y); o.z = f2b(v.z); o.w = f2b(v.w);
  *(ushort4*)(dst + i) = o;
}

// ---------------- X0[t] = emb[idx[:,t+1]] @ W0^T + b0 + bs0, bf16 out ----------------
__global__ __launch_bounds__(256) void k_x0(const float* __restrict__ emb,
                                            const int* __restrict__ ids,
                                            const unsigned short* __restrict__ w0b,
                                            const float* __restrict__ b0,
                                            const float* __restrict__ bs,
                                            unsigned short* __restrict__ x0b) {
  const int t  = blockIdx.x;            // 0..126
  const int cb = blockIdx.y * 256;
  const int lane = threadIdx.x & 63, wvv = threadIdx.x >> 6;
  const int lc = lane & 15, lg = lane >> 4;
  const int cw = cb + wvv * 64;
  const float* erow[4];
#pragma unroll
  for (int rt = 0; rt < 4; ++rt)
    erow[rt] = emb + (size_t)ids[(rt * 16 + lc) * 128 + t + 1] * Hdim + lg * 8;
  f4v acc[4][4];   // [ct][rt]
#pragma unroll
  for (int ct = 0; ct < 4; ++ct)
#pragma unroll
    for (int rt = 0; rt < 4; ++rt) acc[ct][rt] = (f4v){0.f, 0.f, 0.f, 0.f};

  for (int ks = 0; ks < 32; ++ks) {
    s8v bf[4];
#pragma unroll
    for (int rt = 0; rt < 4; ++rt) bf[rt] = pack8(erow[rt] + ks * 32);
#pragma unroll
    for (int ct = 0; ct < 4; ++ct) {
      s8v a = *(const s8v*)(w0b + (size_t)(cw + ct * 16 + lc) * Hdim + ks * 32 + lg * 8);
#pragma unroll
      for (int rt = 0; rt < 4; ++rt)
        acc[ct][rt] = __builtin_amdgcn_mfma_f32_16x16x32_bf16(a, bf[rt], acc[ct][rt], 0, 0, 0);
    }
  }
  unsigned short* xt = x0b + (size_t)t * (64 * Hdim);
#pragma unroll
  for (int ct = 0; ct < 4; ++ct) {
    const int colq = cw + ct * 16 + lg * 4;
    float4 bias = *(const float4*)(b0 + colq);
    float4 bsv  = *(const float4*)(bs + colq);     // bs row 0
#pragma unroll
    for (int rt = 0; rt < 4; ++rt) {
      const int row = rt * 16 + lc;
      ushort4 o;
      o.x = f2b(acc[ct][rt][0] + bias.x + bsv.x);
      o.y = f2b(acc[ct][rt][1] + bias.y + bsv.y);
      o.z = f2b(acc[ct][rt][2] + bias.z + bsv.z);
      o.w = f2b(acc[ct][rt][3] + bias.w + bsv.w);
      *(ushort4*)(xt + (size_t)row * Hdim + colq) = o;
    }
  }
}

// ---------------- persistent scan: 8 XCDs x 2 pipelined 4-row chains ----------------
__global__ __launch_bounds__(256, 1) void k_scan(const float* __restrict__ bs,
                                                 const float* __restrict__ h_in,
                                                 const float* __restrict__ Wsum,
                                                 const float* __restrict__ bsum,
                                                 const float* __restrict__ act,
                                                 char* __restrict__ ws) {
  __shared__ float part[2][4][8][36];    // [out][wave][row][36-pad] (rows 0-3 used)
  __shared__ float n2l[2][4][36];        // leaves per chain
  __shared__ float n4l[2][4][36];
  __shared__ char  pad_lds[81920];       // forces 1 WG/CU -> exactly 32 WG/XCD
  __shared__ int   s_info[2];

  const int tid = threadIdx.x;
  ((volatile char*)pad_lds)[tid] = (char)tid;
  asm volatile("" :: "v"((int)((volatile char*)pad_lds)[tid]));

  const int lane = tid & 63, wv = tid >> 6;
  const int lc = lane & 15, lg = lane >> 4;
  const int lr4 = lc & 3;                // MFMA act row (4-row chain, rows 4..15 dup)

  unsigned* flg_all = (unsigned*)(ws + OFF_FLG);
  unsigned* ranks   = flg_all + 2048;    // after 8*2*4*32 flags

  if (tid == 0) {
    unsigned x;
    asm volatile("s_getreg_b32 %0, hwreg(HW_REG_XCC_ID)" : "=s"(x));
    x &= 7u;
    unsigned rr = __hip_atomic_fetch_add(&ranks[x], 1u, __ATOMIC_RELAXED, __HIP_MEMORY_SCOPE_AGENT);
    s_info[0] = (int)x; s_info[1] = (int)rr;
  }
  __syncthreads();
  const int xcd = s_info[0];
  const int r   = s_info[1];
  if (r >= 32) return;                   // pigeonhole (1 WG/CU) makes this unreachable
  const int c0w = r * 32;

  unsigned short* actX = (unsigned short*)(ws + OFF_ACT) + (size_t)xcd * 32768;
  unsigned* flgX = flg_all + xcd * 256;  // [2 chains][4 groups][32]
  const unsigned short* wsb = (const unsigned short*)(ws + OFF_WSB);
  const unsigned short* x0b = (const unsigned short*)(ws + OFF_X0);
  unsigned short* HB = (unsigned short*)(ws + OFF_HB);

  // softmax combine weights over leaves {2,4,6} -> Wsum rows {1,3,5}
  float cw0, cw1, cw2;
  {
    float c[3];
#pragma unroll
    for (int j = 0; j < 3; ++j) {
      const int i = 2 * j + 1;
      float s = bsum[i];
      for (int a2 = 0; a2 < 12; ++a2) s += Wsum[i * 12 + a2] * act[a2];
      c[j] = s;
    }
    float m = fmaxf(c[0], fmaxf(c[1], c[2]));
    float e0 = __expf(c[0] - m), e1 = __expf(c[1] - m), e2 = __expf(c[2] - m);
    float inv = 1.f / (e0 + e1 + e2);
    cw0 = e0 * inv; cw1 = e1 * inv; cw2 = e2 * inv;
  }

  // ---- preload resident weights Ws[1..5]: per wave 2 col-tiles x 8 k-chunks each ----
  const size_t wbase = (size_t)(c0w + lc) * Hdim + (size_t)wv * 256 + lg * 8;
  const size_t wct   = (size_t)16 * Hdim;
  s8v w1f[2][8], w2f[2][8], w3f[2][8], w4f[2][8], w5f[2][8];
#pragma unroll
  for (int i = 0; i < 8; ++i) {
    w1f[0][i] = *(const s8v*)(wsb + 1u * 1048576u + wbase + i * 32);
    w1f[1][i] = *(const s8v*)(wsb + 1u * 1048576u + wbase + wct + i * 32);
    w2f[0][i] = *(const s8v*)(wsb + 2u * 1048576u + wbase + i * 32);
    w2f[1][i] = *(const s8v*)(wsb + 2u * 1048576u + wbase + wct + i * 32);
    w3f[0][i] = *(const s8v*)(wsb + 3u * 1048576u + wbase + i * 32);
    w3f[1][i] = *(const s8v*)(wsb + 3u * 1048576u + wbase + wct + i * 32);
    w4f[0][i] = *(const s8v*)(wsb + 4u * 1048576u + wbase + i * 32);
    w4f[1][i] = *(const s8v*)(wsb + 4u * 1048576u + wbase + wct + i * 32);
    w5f[0][i] = *(const s8v*)(wsb + 5u * 1048576u + wbase + i * 32);
    w5f[1][i] = *(const s8v*)(wsb + 5u * 1048576u + wbase + wct + i * 32);
  }

  // ---- init: publish h(0) slices for both chains (sc0), flags = 1 ----
  if (tid < 128) {
    const int c = tid >> 6, row4 = (tid >> 4) & 3, cp = (tid & 15) * 2;
    const float* hp = h_in + (size_t)(xcd * 8 + c * 4 + row4) * Hdim + c0w + cp;
    unsigned pk = (unsigned)f2b(hp[0]) | ((unsigned)f2b(hp[1]) << 16);
    st_sc0_u32((unsigned*)(actX + (size_t)c * 16384 + (size_t)row4 * Hdim + c0w + cp), pk);
  }
  wait_vm0();
  __syncthreads();
  if (tid == 0) {
    st_sc1_u32(flgX + 0 * 128 + 96 + r, 1u);
    st_sc1_u32(flgX + 1 * 128 + 96 + r, 1u);
  }

  const f4v z4 = (f4v){0.f, 0.f, 0.f, 0.f};

  for (int t = 0; t < TST; ++t) {
    const unsigned tq = (unsigned)t + 1u;

    // ======== L1: n1 = tanh(Ws0 h + X0[t]) -- chains interleaved ========
#pragma unroll
    for (int c = 0; c < 2; ++c) {
      unsigned short* actC = actX + (size_t)c * 16384;
      unsigned* fgc = flgX + c * 128;
      pollg(fgc + 96, tq);                       // gh of chain c
      {
        s8v bb[8];
        GL8S0(bb, actC + (size_t)lr4 * Hdim + wv * 256 + lg * 8);
        unsigned long long w0a = (unsigned long long)wsb;
        asm volatile("" : "+v"(w0a));            // launder: keep M0 loads in-loop
        const unsigned short* w0p = (const unsigned short*)w0a;
        f4v a0 = z4, a1 = z4;
#pragma unroll
        for (int i = 0; i < 8; ++i) {
          s8v wA = *(const s8v*)(w0p + wbase + i * 32);
          s8v wB = *(const s8v*)(w0p + wbase + wct + i * 32);
          a0 = __builtin_amdgcn_mfma_f32_16x16x32_bf16(wA, bb[i], a0, 0, 0, 0);
          a1 = __builtin_amdgcn_mfma_f32_16x16x32_bf16(wB, bb[i], a1, 0, 0, 0);
        }
        if (lc < 4) {
          *(f4v*)&part[0][wv][lc][lg * 4] = a0;
          *(f4v*)&part[0][wv][lc][16 + lg * 4] = a1;
        }
      }
      __syncthreads();
      if (wv == 0) {
        if (lane < 32) {
          const int rrow = lane & 3, co = (lane >> 2) * 4;
          f4v s = *(f4v*)&part[0][0][rrow][co] + *(f4v*)&part[0][1][rrow][co]
                + *(f4v*)&part[0][2][rrow][co] + *(f4v*)&part[0][3][rrow][co];
          ushort4 xu = *(const ushort4*)(x0b + (size_t)t * 65536 +
                                         (size_t)(xcd * 8 + c * 4 + rrow) * Hdim + c0w + co);
          st_sc0_64(actC + 4096 + (size_t)rrow * Hdim + c0w + co,
                    pk4(fast_tanh(s[0] + b2f(xu.x)), fast_tanh(s[1] + b2f(xu.y)),
                        fast_tanh(s[2] + b2f(xu.z)), fast_tanh(s[3] + b2f(xu.w))));
        }
        wait_vm0();
        if (lane == 0) st_sc1_u32(fgc + 0 + r, tq);   // gn1
      }
      __syncthreads();
    }

    // ======== L2: n3 = sigm(Ws2 n1 + bs2); n2 = relu(Ws1 n1 + bs1) -> LDS ========
#pragma unroll
    for (int c = 0; c < 2; ++c) {
      unsigned short* actC = actX + (size_t)c * 16384;
      unsigned* fgc = flgX + c * 128;
      pollg(fgc + 0, tq);                        // gn1
      {
        s8v bb[8];
        GL8S0(bb, actC + 4096 + (size_t)lr4 * Hdim + wv * 256 + lg * 8);
        f4v a20 = z4, a21 = z4, a10 = z4, a11 = z4;
#pragma unroll
        for (int i = 0; i < 8; ++i) {
          a20 = __builtin_amdgcn_mfma_f32_16x16x32_bf16(w2f[0][i], bb[i], a20, 0, 0, 0);
          a21 = __builtin_amdgcn_mfma_f32_16x16x32_bf16(w2f[1][i], bb[i], a21, 0, 0, 0);
          a10 = __builtin_amdgcn_mfma_f32_16x16x32_bf16(w1f[0][i], bb[i], a10, 0, 0, 0);
          a11 = __builtin_amdgcn_mfma_f32_16x16x32_bf16(w1f[1][i], bb[i], a11, 0, 0, 0);
        }
        if (lc < 4) {
          *(f4v*)&part[0][wv][lc][lg * 4] = a20;
          *(f4v*)&part[0][wv][lc][16 + lg * 4] = a21;
          *(f4v*)&part[1][wv][lc][lg * 4] = a10;
          *(f4v*)&part[1][wv][lc][16 + lg * 4] = a11;
        }
      }
      __syncthreads();
      if (wv == 0) {
        if (lane < 32) {
          const int rrow = lane & 3, co = (lane >> 2) * 4;
          f4v s3 = *(f4v*)&part[0][0][rrow][co] + *(f4v*)&part[0][1][rrow][co]
                 + *(f4v*)&part[0][2][rrow][co] + *(f4v*)&part[0][3][rrow][co];
          f4v b3 = *(const f4v*)(bs + 2 * Hdim + c0w + co);
          st_sc0_64(actC + 8192 + (size_t)rrow * Hdim + c0w + co,
                    pk4(fast_sigm(s3[0] + b3[0]), fast_sigm(s3[1] + b3[1]),
                        fast_sigm(s3[2] + b3[2]), fast_sigm(s3[3] + b3[3])));
        }
        wait_vm0();
        if (lane == 0) st_sc1_u32(fgc + 32 + r, tq);  // gn3
      } else if (wv == 2) {
        if (lane < 32) {
          const int rrow = lane & 3, co = (lane >> 2) * 4;
          f4v s2 = *(f4v*)&part[1][0][rrow][co] + *(f4v*)&part[1][1][rrow][co]
                 + *(f4v*)&part[1][2][rrow][co] + *(f4v*)&part[1][3][rrow][co];
          f4v b2 = *(const f4v*)(bs + 1 * Hdim + c0w + co);
          f4v o; o[0] = fmaxf(s2[0] + b2[0], 0.f); o[1] = fmaxf(s2[1] + b2[1], 0.f);
                 o[2] = fmaxf(s2[2] + b2[2], 0.f); o[3] = fmaxf(s2[3] + b2[3], 0.f);
          *(f4v*)&n2l[c][rrow][co] = o;
        }
      }
      __syncthreads();
    }

    // ======== L3: n5 = relu(Ws4 n3 + bs4); n4 = tanh(Ws3 n3 + bs3) -> LDS ========
#pragma unroll
    for (int c = 0; c < 2; ++c) {
      unsigned short* actC = actX + (size_t)c * 16384;
      unsigned* fgc = flgX + c * 128;
      pollg(fgc + 32, tq);                       // gn3
      {
        s8v bb[8];
        GL8S0(bb, actC + 8192 + (size_t)lr4 * Hdim + wv * 256 + lg * 8);
        f4v a40 = z4, a41 = z4, a30 = z4, a31 = z4;
#pragma unroll
        for (int i = 0; i < 8; ++i) {
          a40 = __builtin_amdgcn_mfma_f32_16x16x32_bf16(w4f[0][i], bb[i], a40, 0, 0, 0);
          a41 = __builtin_amdgcn_mfma_f32_16x16x32_bf16(w4f[1][i], bb[i], a41, 0, 0, 0);
          a30 = __builtin_amdgcn_mfma_f32_16x16x32_bf16(w3f[0][i], bb[i], a30, 0, 0, 0);
          a31 = __builtin_amdgcn_mfma_f32_16x16x32_bf16(w3f[1][i], bb[i], a31, 0, 0, 0);
        }
        if (lc < 4) {
          *(f4v*)&part[0][wv][lc][lg * 4] = a40;
          *(f4v*)&part[0][wv][lc][16 + lg * 4] = a41;
          *(f4v*)&part[1][wv][lc][lg * 4] = a30;
          *(f4v*)&part[1][wv][lc][16 + lg * 4] = a31;
        }
      }
      __syncthreads();
      if (wv == 0) {
        if (lane < 32) {
          const int rrow = lane & 3, co = (lane >> 2) * 4;
          f4v s5 = *(f4v*)&part[0][0][rrow][co] + *(f4v*)&part[0][1][rrow][co]
                 + *(f4v*)&part[0][2][rrow][co] + *(f4v*)&part[0][3][rrow][co];
          f4v b5 = *(const f4v*)(bs + 4 * Hdim + c0w + co);
          st_sc0_64(actC + 12288 + (size_t)rrow * Hdim + c0w + co,
                    pk4(fmaxf(s5[0] + b5[0], 0.f), fmaxf(s5[1] + b5[1], 0.f),
                        fmaxf(s5[2] + b5[2], 0.f), fmaxf(s5[3] + b5[3], 0.f)));
        }
        wait_vm0();
        if (lane == 0) st_sc1_u32(fgc + 64 + r, tq);  // gn5
      } else if (wv == 2) {
        if (lane < 32) {
          const int rrow = lane & 3, co = (lane >> 2) * 4;
          f4v s4 = *(f4v*)&part[1][0][rrow][co] + *(f4v*)&part[1][1][rrow][co]
                 + *(f4v*)&part[1][2][rrow][co] + *(f4v*)&part[1][3][rrow][co];
          f4v b4 = *(const f4v*)(bs + 3 * Hdim + c0w + co);
          f4v o; o[0] = fast_tanh(s4[0] + b4[0]); o[1] = fast_tanh(s4[1] + b4[1]);
                 o[2] = fast_tanh(s4[2] + b4[2]); o[3] = fast_tanh(s4[3] + b4[3]);
          *(f4v*)&n4l[c][rrow][co] = o;
        }
      }
      __syncthreads();
    }

    // ======== L4: n6 = tanh(Ws5 n5 + bs5); h' = cw.(n2l, n4l, n6) ========
#pragma unroll
    for (int c = 0; c < 2; ++c) {
      unsigned short* actC = actX + (size_t)c * 16384;
      unsigned* fgc = flgX + c * 128;
      pollg(fgc + 64, tq);                       // gn5
      {
        s8v bb[8];
        GL8S0(bb, actC + 12288 + (size_t)lr4 * Hdim + wv * 256 + lg * 8);
        f4v a0 = z4, a1 = z4;
#pragma unroll
        for (int i = 0; i < 8; ++i) {
          a0 = __builtin_amdgcn_mfma_f32_16x16x32_bf16(w5f[0][i], bb[i], a0, 0, 0, 0);
          a1 = __builtin_amdgcn_mfma_f32_16x16x32_bf16(w5f[1][i], bb[i], a1, 0, 0, 0);
        }
        if (lc < 4) {
          *(f4v*)&part[0][wv][lc][lg * 4] = a0;
          *(f4v*)&part[0][wv][lc][16 + lg * 4] = a1;
        }
      }
      __syncthreads();
      if (wv == 0) {
        if (lane < 32) {
          const int rrow = lane & 3, co = (lane >> 2) * 4;
          f4v s = *(f4v*)&part[0][0][rrow][co] + *(f4v*)&part[0][1][rrow][co]
                + *(f4v*)&part[0][2][rrow][co] + *(f4v*)&part[0][3][rrow][co];
          f4v b6 = *(const f4v*)(bs + 5 * Hdim + c0w + co);
          float hv[4];
#pragma unroll
          for (int j = 0; j < 4; ++j) {
            const float n6 = fast_tanh(s[j] + b6[j]);
            hv[j] = cw0 * n2l[c][rrow][co + j] + cw1 * n4l[c][rrow][co + j] + cw2 * n6;
          }
          u2v pk = pk4(hv[0], hv[1], hv[2], hv[3]);
          st_sc0_64(actC + (size_t)rrow * Hdim + c0w + co, pk);
          if (t == TST - 1)
            *(u2v*)(HB + (size_t)(xcd * 8 + c * 4 + rrow) * Hdim + c0w + co) = pk;
        }
        wait_vm0();
        if (lane == 0) st_sc1_u32(fgc + 96 + r, tq + 1u);  // gh
      }
      __syncthreads();
    }
  }
}

// ---------------- epilogue: out = h @ W_out^T + b_out ----------------
__global__ __launch_bounds__(256) void k_out(const unsigned short* __restrict__ hb,
                                             const float* __restrict__ wout,
                                             const float* __restrict__ bout,
                                             float* __restrict__ out) {
  const int cb = blockIdx.x * 128;
  const int lane = threadIdx.x & 63, wvv = threadIdx.x >> 6;
  const int lc = lane & 15, lg = lane >> 4;
  const int cw = cb + wvv * 32;
  f4v acc[4][2];
#pragma unroll
  for (int rt = 0; rt < 4; ++rt)
#pragma unroll
    for (int ct = 0; ct < 2; ++ct) acc[rt][ct] = (f4v){0.f, 0.f, 0.f, 0.f};

  for (int ks = 0; ks < 32; ++ks) {
    s8v a[4];
#pragma unroll
    for (int rt = 0; rt < 4; ++rt)
      a[rt] = *(const s8v*)(hb + (rt * 16 + lc) * Hdim + ks * 32 + lg * 8);
#pragma unroll
    for (int ct = 0; ct < 2; ++ct) {
      const int col = cw + ct * 16 + lc;
      const int cs = col < NCLS ? col : NCLS - 1;
      s8v b = pack8(wout + (size_t)cs * Hdim + ks * 32 + lg * 8);
#pragma unroll
      for (int rt = 0; rt < 4; ++rt)
        acc[rt][ct] = __builtin_amdgcn_mfma_f32_16x16x32_bf16(a[rt], b, acc[rt][ct], 0, 0, 0);
    }
  }
#pragma unroll
  for (int ct = 0; ct < 2; ++ct) {
    const int col = cw + ct * 16 + lc;
    if (col < NCLS) {
      const float bias = bout[col];
#pragma unroll
      for (int rt = 0; rt < 4; ++rt)
#pragma unroll
        for (int j = 0; j < 4; ++j)
          out[(size_t)(rt * 16 + lg * 4 + j) * NCLS + col] = acc[rt][ct][j] + bias;
    }
  }
}

extern "C" void kernel_launch(void* const* d_in, const int* in_sizes, int n_in,
                              void* d_out, int out_size, void* d_ws, size_t ws_size,
                              hipStream_t stream) {
  (void)in_sizes; (void)n_in; (void)out_size;
  if (ws_size < WS_NEED) return;

  const float* emb  = (const float*)d_in[0];
  const float* h0   = (const float*)d_in[1];
  const int*   ids  = (const int*)d_in[2];
  const float* W0   = (const float*)d_in[3];
  const float* b0   = (const float*)d_in[4];
  const float* Ws   = (const float*)d_in[5];
  const float* bsp  = (const float*)d_in[6];
  const float* Wout = (const float*)d_in[7];
  const float* bout = (const float*)d_in[8];
  const float* Wsum = (const float*)d_in[9];
  const float* bsum = (const float*)d_in[10];
  const float* actv = (const float*)d_in[11];
  char* ws  = (char*)d_ws;
  float* out = (float*)d_out;

  hipMemsetAsync(ws + OFF_FLG, 0, 16448, stream);                     // flags + ranks
  k_cvt<<<1024, 256, 0, stream>>>(W0, (unsigned short*)(ws + OFF_W0B));
  k_cvt<<<6144, 256, 0, stream>>>(Ws, (unsigned short*)(ws + OFF_WSB));
  k_x0<<<dim3(TST, 4), 256, 0, stream>>>(emb, ids, (const unsigned short*)(ws + OFF_W0B),
                                         b0, bsp, (unsigned short*)(ws + OFF_X0));

  void* args[] = { (void*)&bsp, (void*)&h0, (void*)&Wsum,
                   (void*)&bsum, (void*)&actv, (void*)&ws };
  hipError_t e = hipLaunchCooperativeKernel((void*)k_scan, dim3(256), dim3(256), args, 0, stream);
  if (e != hipSuccess) {
    // fallback: 1 WG/CU forced by ~94 KB LDS -> 256 WGs co-resident anyway;
    // all polls guarded -> worst case wrong answer, never a hang.
    k_scan<<<dim3(256), dim3(256), 0, stream>>>(bsp, h0, Wsum, bsum, actv, ws);
  }

  k_out<<<391, 256, 0, stream>>>((const unsigned short*)(ws + OFF_HB), Wout, bout, out);
}

// Round 16
// 1793.271 us; speedup vs baseline: 2.1087x; 1.5575x over previous
//
#include <hip/hip_runtime.h>
#include <hip/hip_bf16.h>

#define Hdim 1024
#define TST  127
#define NCLS 50000
#define POLL_GUARD (1 << 17)

typedef __attribute__((ext_vector_type(8))) short    s8v;   // 8 x bf16
typedef __attribute__((ext_vector_type(4))) float    f4v;   // MFMA acc
typedef __attribute__((ext_vector_type(2))) unsigned u2v;   // packed 4 x bf16

// ---- workspace layout (bytes) ----
#define OFF_X0   0ull
#define SZ_X0    ((unsigned long long)TST * 64 * Hdim * 2ull)   // 16,646,144 bf16 X0
#define OFF_W0B  (OFF_X0 + SZ_X0)                                // 2 MB bf16 embedding W0
#define OFF_WSB  (OFF_W0B + 2097152ull)                          // 12 MB bf16 Ws[6]
#define OFF_ACT  (OFF_WSB + 12582912ull)                         // 8 xcd x 4 bufs x 16 KB
#define OFF_HB   (OFF_ACT + 524288ull)                           // final h [64][1024] bf16
#define OFF_FLG  (OFF_HB + 131072ull)                            // flags[8][6][32] + ranks[8]
#define WS_NEED  (OFF_FLG + 8192ull)

__device__ __forceinline__ unsigned short f2b(float f) {
  union { float f; unsigned u; } v; v.f = f;
  return (unsigned short)((v.u + 0x7FFFu + ((v.u >> 16) & 1u)) >> 16);  // RNE
}
__device__ __forceinline__ float b2f(unsigned short u) {
  union { unsigned u; float f; } v; v.u = ((unsigned)u) << 16;
  return v.f;
}
__device__ __forceinline__ float fast_tanh(float x) { return 1.f - 2.f / (__expf(2.f * x) + 1.f); }
__device__ __forceinline__ float fast_sigm(float x) { return 1.f / (1.f + __expf(-x)); }
__device__ __forceinline__ s8v pack8(const float* __restrict__ p) {
  s8v r;
#pragma unroll
  for (int i = 0; i < 8; ++i) r[i] = (short)f2b(p[i]);
  return r;
}
__device__ __forceinline__ u2v pk4(float a, float b, float c, float d) {
  u2v v;
  v[0] = (unsigned)f2b(a) | ((unsigned)f2b(b) << 16);
  v[1] = (unsigned)f2b(c) | ((unsigned)f2b(d) << 16);
  return v;
}

// ---- access helpers: sc1 = L3 coherence point; sc0 = L1-bypass, own-XCD L2 ----
__device__ __forceinline__ void st_sc1_u32(unsigned* p, unsigned v) {
  asm volatile("global_store_dword %0, %1, off sc0 sc1" :: "v"(p), "v"(v) : "memory");
}
__device__ __forceinline__ void st_sc0_u32(unsigned* p, unsigned v) {
  asm volatile("global_store_dword %0, %1, off sc0" :: "v"(p), "v"(v) : "memory");
}
__device__ __forceinline__ void st_sc0_64(unsigned short* p, u2v v) {
  asm volatile("global_store_dwordx2 %0, %1, off sc0" :: "v"(p), "v"(v) : "memory");
}
__device__ __forceinline__ void wait_vm0() { asm volatile("s_waitcnt vmcnt(0)" ::: "memory"); }

// poll 32 sc1 flags (lane & 31) >= tgt; one load + drain per iter (R3 lesson: one block)
__device__ __forceinline__ void pollg(const unsigned* fb, unsigned tgt) {
  const unsigned* p = fb + (threadIdx.x & 31);
  int gd = 0;
  for (;;) {
    unsigned v;
    asm volatile("global_load_dword %0, %1, off sc0 sc1\n\ts_waitcnt vmcnt(0)"
                 : "=v"(v) : "v"(p) : "memory");
    if (__all((int)(v >= tgt))) break;
    if (++gd >= POLL_GUARD) break;
  }
}

// 8 sc0 dwordx4 act loads + drain in ONE asm block (9 operands, proven scale)
#define GL8S0(B, P) asm volatile(                                       \
  "global_load_dwordx4 %0, %8, off sc0\n\t"                             \
  "global_load_dwordx4 %1, %8, off offset:64 sc0\n\t"                   \
  "global_load_dwordx4 %2, %8, off offset:128 sc0\n\t"                  \
  "global_load_dwordx4 %3, %8, off offset:192 sc0\n\t"                  \
  "global_load_dwordx4 %4, %8, off offset:256 sc0\n\t"                  \
  "global_load_dwordx4 %5, %8, off offset:320 sc0\n\t"                  \
  "global_load_dwordx4 %6, %8, off offset:384 sc0\n\t"                  \
  "global_load_dwordx4 %7, %8, off offset:448 sc0\n\t"                  \
  "s_waitcnt vmcnt(0)"                                                  \
  : "=&v"(B[0]), "=&v"(B[1]), "=&v"(B[2]), "=&v"(B[3]),                 \
    "=&v"(B[4]), "=&v"(B[5]), "=&v"(B[6]), "=&v"(B[7])                  \
  : "v"(P) : "memory")

// ---------------- fp32 -> bf16 bulk convert (W0 and Ws) ----------------
__global__ __launch_bounds__(256) void k_cvt(const float* __restrict__ src,
                                             unsigned short* __restrict__ dst) {
  const int i = (blockIdx.x * 256 + threadIdx.x) * 4;
  float4 v = *(const float4*)(src + i);
  ushort4 o; o.x = f2b(v.x); o.y = f2b(v.y); o.z = f2b(v.z); o.w = f2b(v.w);
  *(ushort4*)(dst + i) = o;
}

// ---------------- X0[t] = emb[idx[:,t+1]] @ W0^T + b0 + bs0, bf16 out ----------------
__global__ __launch_bounds__(256) void k_x0(const float* __restrict__ emb,
                                            const int* __restrict__ ids,
                                            const unsigned short* __restrict__ w0b,
                                            const float* __restrict__ b0,
                                            const float* __restrict__ bs,
                                            unsigned short* __restrict__ x0b) {
  const int t  = blockIdx.x;            // 0..126
  const int cb = blockIdx.y * 256;
  const int lane = threadIdx.x & 63, wvv = threadIdx.x >> 6;
  const int lc = lane & 15, lg = lane >> 4;
  const int cw = cb + wvv * 64;
  const float* erow[4];
#pragma unroll
  for (int rt = 0; rt < 4; ++rt)
    erow[rt] = emb + (size_t)ids[(rt * 16 + lc) * 128 + t + 1] * Hdim + lg * 8;
  f4v acc[4][4];   // [ct][rt]
#pragma unroll
  for (int ct = 0; ct < 4; ++ct)
#pragma unroll
    for (int rt = 0; rt < 4; ++rt) acc[ct][rt] = (f4v){0.f, 0.f, 0.f, 0.f};

  for (int ks = 0; ks < 32; ++ks) {
    s8v bf[4];
#pragma unroll
    for (int rt = 0; rt < 4; ++rt) bf[rt] = pack8(erow[rt] + ks * 32);
#pragma unroll
    for (int ct = 0; ct < 4; ++ct) {
      s8v a = *(const s8v*)(w0b + (size_t)(cw + ct * 16 + lc) * Hdim + ks * 32 + lg * 8);
#pragma unroll
      for (int rt = 0; rt < 4; ++rt)
        acc[ct][rt] = __builtin_amdgcn_mfma_f32_16x16x32_bf16(a, bf[rt], acc[ct][rt], 0, 0, 0);
    }
  }
  unsigned short* xt = x0b + (size_t)t * (64 * Hdim);
#pragma unroll
  for (int ct = 0; ct < 4; ++ct) {
    const int colq = cw + ct * 16 + lg * 4;
    float4 bias = *(const float4*)(b0 + colq);
    float4 bsv  = *(const float4*)(bs + colq);     // bs row 0
#pragma unroll
    for (int rt = 0; rt < 4; ++rt) {
      const int row = rt * 16 + lc;
      ushort4 o;
      o.x = f2b(acc[ct][rt][0] + bias.x + bsv.x);
      o.y = f2b(acc[ct][rt][1] + bias.y + bsv.y);
      o.z = f2b(acc[ct][rt][2] + bias.z + bsv.z);
      o.w = f2b(acc[ct][rt][3] + bias.w + bsv.w);
      *(ushort4*)(xt + (size_t)row * Hdim + colq) = o;
    }
  }
}

// ---------------- persistent scan: 8 independent XCD-local row chains ----------------
__global__ __launch_bounds__(256, 1) void k_scan(const float* __restrict__ bs,
                                                 const float* __restrict__ h_in,
                                                 const float* __restrict__ Wsum,
                                                 const float* __restrict__ bsum,
                                                 const float* __restrict__ act,
                                                 char* __restrict__ ws) {
  __shared__ float part[2][4][8][36];    // padded stride 144B: 2-way (free) reduce reads
  __shared__ float n2l[8][36];
  __shared__ float n4l[8][36];
  __shared__ char  pad_lds[81920];       // forces 1 WG/CU -> exactly 32 WG/XCD
  __shared__ int   s_info[2];

  const int tid = threadIdx.x;
  ((volatile char*)pad_lds)[tid] = (char)tid;              // volatile: not eliminable
  asm volatile("" :: "v"((int)((volatile char*)pad_lds)[tid]));

  const int lane = tid & 63, wv = tid >> 6;
  const int lc = lane & 15, lg = lane >> 4;
  const int lr = lc & 7;                 // act row (rows 8..15 duplicate 0..7)
  const int lcr = lc & 7, ctx = lc >> 3; // reduce remap: all 64 lanes active
  const int cbx = ctx * 16 + lg * 4;     // this lane's 4-col quad in the 32-col slab

  unsigned* flg_all = (unsigned*)(ws + OFF_FLG);
  unsigned* ranks   = flg_all + 1536;

  if (tid == 0) {
    unsigned x;
    asm volatile("s_getreg_b32 %0, hwreg(HW_REG_XCC_ID)" : "=s"(x));
    x &= 7u;
    unsigned rr = __hip_atomic_fetch_add(&ranks[x], 1u, __ATOMIC_RELAXED, __HIP_MEMORY_SCOPE_AGENT);
    s_info[0] = (int)x; s_info[1] = (int)rr;
  }
  __syncthreads();
  const int xcd = s_info[0];
  const int r   = s_info[1];
  if (r >= 32) return;                   // pigeonhole (1 WG/CU) makes this unreachable
  const int c0w = r * 32;

  unsigned short* actX = (unsigned short*)(ws + OFF_ACT) + (size_t)xcd * 32768;
  unsigned short* hL  = actX;            // [8][1024] bf16 per buffer
  unsigned short* n1L = actX + 8192;
  unsigned short* n3L = actX + 16384;
  unsigned short* n5L = actX + 24576;
  unsigned* flgX = flg_all + xcd * 192;  // [6][32]
  unsigned* fg0 = flgX;                  // n1
  unsigned* fg2 = flgX + 64;             // n3
  unsigned* fg4 = flgX + 128;            // n5
  unsigned* fg5 = flgX + 160;            // h
  const unsigned short* wsb = (const unsigned short*)(ws + OFF_WSB);
  const unsigned short* x0b = (const unsigned short*)(ws + OFF_X0);
  unsigned short* HB = (unsigned short*)(ws + OFF_HB);

  // softmax combine weights over leaves {2,4,6} -> Wsum rows {1,3,5}
  float cw0, cw1, cw2;
  {
    float c[3];
#pragma unroll
    for (int j = 0; j < 3; ++j) {
      const int i = 2 * j + 1;
      float s = bsum[i];
      for (int a2 = 0; a2 < 12; ++a2) s += Wsum[i * 12 + a2] * act[a2];
      c[j] = s;
    }
    float m = fmaxf(c[0], fmaxf(c[1], c[2]));
    float e0 = __expf(c[0] - m), e1 = __expf(c[1] - m), e2 = __expf(c[2] - m);
    float inv = 1.f / (e0 + e1 + e2);
    cw0 = e0 * inv; cw1 = e1 * inv; cw2 = e2 * inv;
  }

  // ---- preload resident weights Ws[1..5]: per wave 2 col-tiles x 8 k-chunks each ----
  const size_t wbase = (size_t)(c0w + lc) * Hdim + (size_t)wv * 256 + lg * 8;
  const size_t wct   = (size_t)16 * Hdim;
  s8v w1f[2][8], w2f[2][8], w3f[2][8], w4f[2][8], w5f[2][8];
#pragma unroll
  for (int i = 0; i < 8; ++i) {
    w1f[0][i] = *(const s8v*)(wsb + 1u * 1048576u + wbase + i * 32);
    w1f[1][i] = *(const s8v*)(wsb + 1u * 1048576u + wbase + wct + i * 32);
    w2f[0][i] = *(const s8v*)(wsb + 2u * 1048576u + wbase + i * 32);
    w2f[1][i] = *(const s8v*)(wsb + 2u * 1048576u + wbase + wct + i * 32);
    w3f[0][i] = *(const s8v*)(wsb + 3u * 1048576u + wbase + i * 32);
    w3f[1][i] = *(const s8v*)(wsb + 3u * 1048576u + wbase + wct + i * 32);
    w4f[0][i] = *(const s8v*)(wsb + 4u * 1048576u + wbase + i * 32);
    w4f[1][i] = *(const s8v*)(wsb + 4u * 1048576u + wbase + wct + i * 32);
    w5f[0][i] = *(const s8v*)(wsb + 5u * 1048576u + wbase + i * 32);
    w5f[1][i] = *(const s8v*)(wsb + 5u * 1048576u + wbase + wct + i * 32);
  }

  // ---- init: publish h(0) slice (sc0, own L2), flag g5 = 1 ----
  if (tid < 128) {
    const int row = tid >> 4, cp = (tid & 15) * 2;
    const float* hp = h_in + (size_t)(xcd * 8 + row) * Hdim + c0w + cp;
    unsigned pk = (unsigned)f2b(hp[0]) | ((unsigned)f2b(hp[1]) << 16);
    st_sc0_u32((unsigned*)(hL + (size_t)row * Hdim + c0w + cp), pk);
  }
  wait_vm0();
  __syncthreads();
  if (tid == 0) st_sc1_u32(fg5 + r, 1u);

  const f4v z4 = (f4v){0.f, 0.f, 0.f, 0.f};

  for (int t = 0; t < TST; ++t) {
    // ======== L1: n1 = tanh(Ws0 h + X0[t])  (Ws0 streamed) ========
    if (wv == 0) pollg(fg5, (unsigned)t + 1u);   // wave0-only: 4x less flag-line traffic
    __syncthreads();
    {
      s8v bb[8];
      GL8S0(bb, hL + (size_t)lr * Hdim + wv * 256 + lg * 8);
      unsigned long long w0a = (unsigned long long)wsb;
      asm volatile("" : "+v"(w0a));                  // launder: keep M0 loads in-loop
      const unsigned short* w0p = (const unsigned short*)w0a;
      f4v a0 = z4, a1 = z4;
#pragma unroll
      for (int i = 0; i < 8; ++i) {
        s8v wA = *(const s8v*)(w0p + wbase + i * 32);
        s8v wB = *(const s8v*)(w0p + wbase + wct + i * 32);
        a0 = __builtin_amdgcn_mfma_f32_16x16x32_bf16(wA, bb[i], a0, 0, 0, 0);
        a1 = __builtin_amdgcn_mfma_f32_16x16x32_bf16(wB, bb[i], a1, 0, 0, 0);
      }
      if (lc < 8) {
        *(f4v*)&part[0][wv][lc][lg * 4] = a0;
        *(f4v*)&part[0][wv][lc][16 + lg * 4] = a1;
      }
    }
    __syncthreads();
    if (wv == 0) {
      f4v s = *(f4v*)&part[0][0][lcr][cbx] + *(f4v*)&part[0][1][lcr][cbx]
            + *(f4v*)&part[0][2][lcr][cbx] + *(f4v*)&part[0][3][lcr][cbx];
      ushort4 xu = *(const ushort4*)(x0b + (size_t)t * 65536 +
                                     (size_t)(xcd * 8 + lcr) * Hdim + c0w + cbx);
      st_sc0_64(n1L + (size_t)lcr * Hdim + c0w + cbx,
                pk4(fast_tanh(s[0] + b2f(xu.x)), fast_tanh(s[1] + b2f(xu.y)),
                    fast_tanh(s[2] + b2f(xu.z)), fast_tanh(s[3] + b2f(xu.w))));
      wait_vm0();
      if (lane == 0) st_sc1_u32(fg0 + r, (unsigned)t + 1u);
    }
    __syncthreads();

    // ======== L2: n3 = sigm(Ws2 n1 + bs2); n2 = relu(Ws1 n1 + bs1) -> LDS ========
    if (wv == 0) pollg(fg0, (unsigned)t + 1u);
    __syncthreads();
    {
      s8v bb[8];
      GL8S0(bb, n1L + (size_t)lr * Hdim + wv * 256 + lg * 8);
      f4v a20 = z4, a21 = z4, a10 = z4, a11 = z4;
#pragma unroll
      for (int i = 0; i < 8; ++i) {
        a20 = __builtin_amdgcn_mfma_f32_16x16x32_bf16(w2f[0][i], bb[i], a20, 0, 0, 0);
        a21 = __builtin_amdgcn_mfma_f32_16x16x32_bf16(w2f[1][i], bb[i], a21, 0, 0, 0);
        a10 = __builtin_amdgcn_mfma_f32_16x16x32_bf16(w1f[0][i], bb[i], a10, 0, 0, 0);
        a11 = __builtin_amdgcn_mfma_f32_16x16x32_bf16(w1f[1][i], bb[i], a11, 0, 0, 0);
      }
      if (lc < 8) {
        *(f4v*)&part[0][wv][lc][lg * 4] = a20;
        *(f4v*)&part[0][wv][lc][16 + lg * 4] = a21;
        *(f4v*)&part[1][wv][lc][lg * 4] = a10;
        *(f4v*)&part[1][wv][lc][16 + lg * 4] = a11;
      }
    }
    __syncthreads();
    if (wv == 0) {
      f4v s = *(f4v*)&part[0][0][lcr][cbx] + *(f4v*)&part[0][1][lcr][cbx]
            + *(f4v*)&part[0][2][lcr][cbx] + *(f4v*)&part[0][3][lcr][cbx];
      f4v b = *(const f4v*)(bs + 2 * Hdim + c0w + cbx);
      st_sc0_64(n3L + (size_t)lcr * Hdim + c0w + cbx,
                pk4(fast_sigm(s[0] + b[0]), fast_sigm(s[1] + b[1]),
                    fast_sigm(s[2] + b[2]), fast_sigm(s[3] + b[3])));
      wait_vm0();
      if (lane == 0) st_sc1_u32(fg2 + r, (unsigned)t + 1u);
    } else if (wv == 2) {
      f4v s = *(f4v*)&part[1][0][lcr][cbx] + *(f4v*)&part[1][1][lcr][cbx]
            + *(f4v*)&part[1][2][lcr][cbx] + *(f4v*)&part[1][3][lcr][cbx];
      f4v b = *(const f4v*)(bs + 1 * Hdim + c0w + cbx);
      f4v o; o[0] = fmaxf(s[0] + b[0], 0.f); o[1] = fmaxf(s[1] + b[1], 0.f);
             o[2] = fmaxf(s[2] + b[2], 0.f); o[3] = fmaxf(s[3] + b[3], 0.f);
      *(f4v*)&n2l[lcr][cbx] = o;
    }
    __syncthreads();

    // ======== L3: n5 = relu(Ws4 n3 + bs4); n4 = tanh(Ws3 n3 + bs3) -> LDS ========
    if (wv == 0) pollg(fg2, (unsigned)t + 1u);
    __syncthreads();
    {
      s8v bb[8];
      GL8S0(bb, n3L + (size_t)lr * Hdim + wv * 256 + lg * 8);
      f4v a40 = z4, a41 = z4, a30 = z4, a31 = z4;
#pragma unroll
      for (int i = 0; i < 8; ++i) {
        a40 = __builtin_amdgcn_mfma_f32_16x16x32_bf16(w4f[0][i], bb[i], a40, 0, 0, 0);
        a41 = __builtin_amdgcn_mfma_f32_16x16x32_bf16(w4f[1][i], bb[i], a41, 0, 0, 0);
        a30 = __builtin_amdgcn_mfma_f32_16x16x32_bf16(w3f[0][i], bb[i], a30, 0, 0, 0);
        a31 = __builtin_amdgcn_mfma_f32_16x16x32_bf16(w3f[1][i], bb[i], a31, 0, 0, 0);
      }
      if (lc < 8) {
        *(f4v*)&part[0][wv][lc][lg * 4] = a40;
        *(f4v*)&part[0][wv][lc][16 + lg * 4] = a41;
        *(f4v*)&part[1][wv][lc][lg * 4] = a30;
        *(f4v*)&part[1][wv][lc][16 + lg * 4] = a31;
      }
    }
    __syncthreads();
    if (wv == 0) {
      f4v s = *(f4v*)&part[0][0][lcr][cbx] + *(f4v*)&part[0][1][lcr][cbx]
            + *(f4v*)&part[0][2][lcr][cbx] + *(f4v*)&part[0][3][lcr][cbx];
      f4v b = *(const f4v*)(bs + 4 * Hdim + c0w + cbx);
      st_sc0_64(n5L + (size_t)lcr * Hdim + c0w + cbx,
                pk4(fmaxf(s[0] + b[0], 0.f), fmaxf(s[1] + b[1], 0.f),
                    fmaxf(s[2] + b[2], 0.f), fmaxf(s[3] + b[3], 0.f)));
      wait_vm0();
      if (lane == 0) st_sc1_u32(fg4 + r, (unsigned)t + 1u);
    } else if (wv == 2) {
      f4v s = *(f4v*)&part[1][0][lcr][cbx] + *(f4v*)&part[1][1][lcr][cbx]
            + *(f4v*)&part[1][2][lcr][cbx] + *(f4v*)&part[1][3][lcr][cbx];
      f4v b = *(const f4v*)(bs + 3 * Hdim + c0w + cbx);
      f4v o; o[0] = fast_tanh(s[0] + b[0]); o[1] = fast_tanh(s[1] + b[1]);
             o[2] = fast_tanh(s[2] + b[2]); o[3] = fast_tanh(s[3] + b[3]);
      *(f4v*)&n4l[lcr][cbx] = o;
    }
    __syncthreads();

    // ======== L4: n6 = tanh(Ws5 n5 + bs5); h' = cw.(n2,n4,n6) ========
    if (wv == 0) pollg(fg4, (unsigned)t + 1u);
    __syncthreads();
    {
      s8v bb[8];
      GL8S0(bb, n5L + (size_t)lr * Hdim + wv * 256 + lg * 8);
      f4v a0 = z4, a1 = z4;
#pragma unroll
      for (int i = 0; i < 8; ++i) {
        a0 = __builtin_amdgcn_mfma_f32_16x16x32_bf16(w5f[0][i], bb[i], a0, 0, 0, 0);
        a1 = __builtin_amdgcn_mfma_f32_16x16x32_bf16(w5f[1][i], bb[i], a1, 0, 0, 0);
      }
      if (lc < 8) {
        *(f4v*)&part[0][wv][lc][lg * 4] = a0;
        *(f4v*)&part[0][wv][lc][16 + lg * 4] = a1;
      }
    }
    __syncthreads();
    if (wv == 0) {
      f4v s = *(f4v*)&part[0][0][lcr][cbx] + *(f4v*)&part[0][1][lcr][cbx]
            + *(f4v*)&part[0][2][lcr][cbx] + *(f4v*)&part[0][3][lcr][cbx];
      f4v b = *(const f4v*)(bs + 5 * Hdim + c0w + cbx);
      float hv[4];
#pragma unroll
      for (int j = 0; j < 4; ++j) {
        const float n6 = fast_tanh(s[j] + b[j]);
        hv[j] = cw0 * n2l[lcr][cbx + j] + cw1 * n4l[lcr][cbx + j] + cw2 * n6;
      }
      u2v pk = pk4(hv[0], hv[1], hv[2], hv[3]);
      st_sc0_64(hL + (size_t)lcr * Hdim + c0w + cbx, pk);
      if (t == TST - 1)
        *(u2v*)(HB + (size_t)(xcd * 8 + lcr) * Hdim + c0w + cbx) = pk;
      wait_vm0();
      if (lane == 0) st_sc1_u32(fg5 + r, (unsigned)t + 2u);
    }
    __syncthreads();
  }
}

// ---------------- epilogue: out = h @ W_out^T + b_out ----------------
__global__ __launch_bounds__(256) void k_out(const unsigned short* __restrict__ hb,
                                             const float* __restrict__ wout,
                                             const float* __restrict__ bout,
                                             float* __restrict__ out) {
  const int cb = blockIdx.x * 128;
  const int lane = threadIdx.x & 63, wvv = threadIdx.x >> 6;
  const int lc = lane & 15, lg = lane >> 4;
  const int cw = cb + wvv * 32;
  f4v acc[4][2];
#pragma unroll
  for (int rt = 0; rt < 4; ++rt)
#pragma unroll
    for (int ct = 0; ct < 2; ++ct) acc[rt][ct] = (f4v){0.f, 0.f, 0.f, 0.f};

  for (int ks = 0; ks < 32; ++ks) {
    s8v a[4];
#pragma unroll
    for (int rt = 0; rt < 4; ++rt)
      a[rt] = *(const s8v*)(hb + (rt * 16 + lc) * Hdim + ks * 32 + lg * 8);
#pragma unroll
    for (int ct = 0; ct < 2; ++ct) {
      const int col = cw + ct * 16 + lc;
      const int cs = col < NCLS ? col : NCLS - 1;
      s8v b = pack8(wout + (size_t)cs * Hdim + ks * 32 + lg * 8);
#pragma unroll
      for (int rt = 0; rt < 4; ++rt)
        acc[rt][ct] = __builtin_amdgcn_mfma_f32_16x16x32_bf16(a[rt], b, acc[rt][ct], 0, 0, 0);
    }
  }
#pragma unroll
  for (int ct = 0; ct < 2; ++ct) {
    const int col = cw + ct * 16 + lc;
    if (col < NCLS) {
      const float bias = bout[col];
#pragma unroll
      for (int rt = 0; rt < 4; ++rt)
#pragma unroll
        for (int j = 0; j < 4; ++j)
          out[(size_t)(rt * 16 + lg * 4 + j) * NCLS + col] = acc[rt][ct][j] + bias;
    }
  }
}

extern "C" void kernel_launch(void* const* d_in, const int* in_sizes, int n_in,
                              void* d_out, int out_size, void* d_ws, size_t ws_size,
                              hipStream_t stream) {
  (void)in_sizes; (void)n_in; (void)out_size;
  if (ws_size < WS_NEED) return;

  const float* emb  = (const float*)d_in[0];
  const float* h0   = (const float*)d_in[1];
  const int*   ids  = (const int*)d_in[2];
  const float* W0   = (const float*)d_in[3];
  const float* b0   = (const float*)d_in[4];
  const float* Ws   = (const float*)d_in[5];
  const float* bsp  = (const float*)d_in[6];
  const float* Wout = (const float*)d_in[7];
  const float* bout = (const float*)d_in[8];
  const float* Wsum = (const float*)d_in[9];
  const float* bsum = (const float*)d_in[10];
  const float* actv = (const float*)d_in[11];
  char* ws  = (char*)d_ws;
  float* out = (float*)d_out;

  hipMemsetAsync(ws + OFF_FLG, 0, 8192, stream);                      // flags + ranks
  k_cvt<<<1024, 256, 0, stream>>>(W0, (unsigned short*)(ws + OFF_W0B));
  k_cvt<<<6144, 256, 0, stream>>>(Ws, (unsigned short*)(ws + OFF_WSB));
  k_x0<<<dim3(TST, 4), 256, 0, stream>>>(emb, ids, (const unsigned short*)(ws + OFF_W0B),
                                         b0, bsp, (unsigned short*)(ws + OFF_X0));

  void* args[] = { (void*)&bsp, (void*)&h0, (void*)&Wsum,
                   (void*)&bsum, (void*)&actv, (void*)&ws };
  hipError_t e = hipLaunchCooperativeKernel((void*)k_scan, dim3(256), dim3(256), args, 0, stream);
  if (e != hipSuccess) {
    // fallback: 1 WG/CU forced by ~93 KB LDS -> 256 WGs co-resident anyway;
    // all polls guarded -> worst case wrong answer, never a hang.
    k_scan<<<dim3(256), dim3(256), 0, stream>>>(bsp, h0, Wsum, bsum, actv, ws);
  }

  k_out<<<391, 256, 0, stream>>>((const unsigned short*)(ws + OFF_HB), Wout, bout, out);
}